// Round 4
// baseline (18.990 us; speedup 1.0000x reference)
//
#include <hip/hip_runtime.h>
#include <math.h>

namespace {

typedef __attribute__((ext_vector_type(2))) float f32x2;

constexpr int H = 128, W = 128;

// ---------- packed fp32 (VOP3P) with op_sel scalar-broadcast ----------
__device__ __forceinline__ f32x2 pk_mul_x(f32x2 a, f32x2 b) {
    f32x2 d; asm("v_pk_mul_f32 %0, %1, %2 op_sel:[0,0] op_sel_hi:[0,1]"
                 : "=v"(d) : "v"(a), "v"(b)); return d;
}
__device__ __forceinline__ f32x2 pk_fma_x(f32x2 a, f32x2 b, f32x2 c) {
    f32x2 d; asm("v_pk_fma_f32 %0, %1, %2, %3 op_sel:[0,0,0] op_sel_hi:[0,1,1]"
                 : "=v"(d) : "v"(a), "v"(b), "v"(c)); return d;
}
__device__ __forceinline__ f32x2 pk_fma_y(f32x2 a, f32x2 b, f32x2 c) {
    f32x2 d; asm("v_pk_fma_f32 %0, %1, %2, %3 op_sel:[1,0,0] op_sel_hi:[1,1,1]"
                 : "=v"(d) : "v"(a), "v"(b), "v"(c)); return d;
}
__device__ __forceinline__ f32x2 pk_fnma_y(f32x2 a, f32x2 b, f32x2 c) {
    f32x2 d; asm("v_pk_fma_f32 %0, %1, %2, %3 op_sel:[1,0,0] op_sel_hi:[1,1,1] neg_lo:[1,0,0] neg_hi:[1,0,0]"
                 : "=v"(d) : "v"(a), "v"(b), "v"(c)); return d;
}
// d = c + a.y * (i*b)
__device__ __forceinline__ f32x2 pk_fma_im(f32x2 a, f32x2 b, f32x2 c) {
    f32x2 d; asm("v_pk_fma_f32 %0, %1, %2, %3 op_sel:[1,1,0] op_sel_hi:[1,0,1] neg_lo:[0,1,0]"
                 : "=v"(d) : "v"(a), "v"(b), "v"(c)); return d;
}
__device__ __forceinline__ f32x2 cmul(f32x2 m, f32x2 v) { return pk_fma_im(m, v, pk_mul_x(m, v)); }
__device__ __forceinline__ f32x2 cfma(f32x2 m, f32x2 v, f32x2 a) { return pk_fma_im(m, v, pk_fma_x(m, v, a)); }

// ---------- partner-lane exchange (lanes 2m <-> 2m+1), DPP quad_perm [1,0,3,2] ----------
__device__ __forceinline__ float dpp1(float v) {
    return __int_as_float(__builtin_amdgcn_update_dpp(0, __float_as_int(v), 0xB1, 0xF, 0xF, true));
}
__device__ __forceinline__ f32x2 xpair(f32x2 v) { f32x2 r; r.x = dpp1(v.x); r.y = dpp1(v.y); return r; }

__device__ __forceinline__ float rsq(float x) { return __builtin_amdgcn_rsqf(x); }

#define RYP(i0, i1) { const f32x2 v0 = st[i0], v1 = st[i1];                         \
    st[i0] = pk_fnma_y(cs, v1, pk_mul_x(cs, v0));                                    \
    st[i1] = pk_fma_y(cs, v0, pk_mul_x(cs, v1)); }

#define ROTP(i0, i1) { const f32x2 v0 = st[i0], v1 = st[i1];                        \
    st[i0] = cfma(M01, v1, cmul(M00, v0));                                           \
    st[i1] = cfma(M11, v1, cmul(M10, v0)); }

#define SWAPV(a, b) { const f32x2 _t = (a); (a) = (b); (b) = _t; }

template <int M>
__device__ __forceinline__ void cswap_local(f32x2* st, bool hi) {
#pragma unroll
    for (int k = 0; k < 8; ++k) {
        if ((k & M) == 0) {
            const f32x2 A = st[k], B = st[k | M];
            st[k] = hi ? B : A;
            st[k | M] = hi ? A : B;
        }
    }
}
template <int M>
__device__ __forceinline__ void cx0(f32x2* st) {
#pragma unroll
    for (int k = 0; k < 8; ++k)
        if (k & M) st[k] = xpair(st[k]);
}

__device__ __forceinline__ void load9(float* a, const float* __restrict__ xc, int i, int j) {
#pragma unroll
    for (int di = 0; di < 3; ++di) {
#pragma unroll
        for (int dj = 0; dj < 3; ++dj) {
            const int y = i + di - 1, z = j + dj - 1;
            float v = 0.f;
            if ((unsigned)y < (unsigned)H && (unsigned)z < (unsigned)W) v = xc[(y << 7) + z];
            a[di * 3 + dj] = v + 0.01f;
        }
    }
}

// Mottonen cascade, split form. All (c,s) built from per-node rsq only:
// c = t_lo*rsq(t_lo)*rsq(t_parent), leaves use sqrt(p_k) = a_k exactly.
__device__ __forceinline__ void cascade(f32x2* st, const float* a, bool hi) {
    float p[9];
#pragma unroll
    for (int k = 0; k < 9; ++k) p[k] = a[k] * a[k];
    const float t10 = p[0] + p[1], t11 = p[2] + p[3], t12 = p[4] + p[5], t13 = p[6] + p[7];
    const float t14 = p[8] + 1e-4f;
    const float t20 = t10 + t11, t21 = t12 + t13, t22 = t14 + 2e-4f;
    const float t30 = t20 + t21, t31 = t22 + 4e-4f;

    const float r30 = rsq(t30), r31 = rsq(t31);
    const float r20 = rsq(t20), r21 = rsq(t21), r22 = rsq(t22);
    const float r10 = rsq(t10), r11 = rsq(t11), r12 = rsq(t12), r13 = rsq(t13), r14 = rsq(t14);

    constexpr float RH = 0.70710678118654752f;

    // q0 (cross): c = n(t30)*R, s = n(t31)*R, R = rsq(t30+t31)
    {
        const float R = rsq(t30 + t31);
        f32x2 cs0; cs0.x = t30 * r30 * R; cs0.y = t31 * r31 * R;
        cs0.y = hi ? cs0.y : -cs0.y;
#pragma unroll
        for (int k = 0; k < 8; ++k) {
            const f32x2 w = xpair(st[k]);
            st[k] = pk_fma_y(cs0, w, pk_mul_x(cs0, st[k]));
        }
    }
    // q1 (mask 4): A: (n20, n21)*r30 ; B: (n22, 2e-2)*r31
    {
        const float rp = hi ? r31 : r30;
        f32x2 cs; cs.x = (hi ? t22 * r22 : t20 * r20) * rp;
        cs.y = (hi ? 2e-2f : t21 * r21) * rp;
        RYP(0, 4) RYP(1, 5) RYP(2, 6) RYP(3, 7)
    }
    // q2 (mask 2), slots 0-3: A: (n10, n11)*r20 ; B: (n14, sqrt(2e-4))*r22
    {
        const float rp = hi ? r22 : r20;
        f32x2 cs; cs.x = (hi ? t14 * r14 : t10 * r10) * rp;
        cs.y = (hi ? 1.41421356e-2f : t11 * r11) * rp;
        RYP(0, 2) RYP(1, 3)
    }
    // q2, slots 4-7: A: (n12, n13)*r21 ; B: (RH, RH)
    {
        f32x2 cs; cs.x = hi ? RH : t12 * r12 * r21;
        cs.y = hi ? RH : t13 * r13 * r21;
        RYP(4, 6) RYP(5, 7)
    }
    // q3 (mask 1): leaves, sqrt(p_k) = a_k
    { f32x2 cs; cs.x = (hi ? a[8] : a[0]) * (hi ? r14 : r10);
      cs.y = (hi ? 0.01f : a[1]) * (hi ? r14 : r10); RYP(0, 1) }
    { f32x2 cs; cs.x = hi ? RH : a[2] * r11; cs.y = hi ? RH : a[3] * r11; RYP(2, 3) }
    { f32x2 cs; cs.x = hi ? RH : a[4] * r12; cs.y = hi ? RH : a[5] * r12; RYP(4, 5) }
    { f32x2 cs; cs.x = hi ? RH : a[6] * r13; cs.y = hi ? RH : a[7] * r13; RYP(6, 7) }
}

__device__ __forceinline__ void rot_layer(f32x2* st, const f32x2* __restrict__ mats,
                                          int base, int u) {
    {   // wire 0 (cross): A: o = m00*v + m01*w ; B: o = m11*v + m10*w
        const f32x2 ma = mats[base + 3 * u], mb = mats[base + 1 + u];
#pragma unroll
        for (int k = 0; k < 8; ++k) {
            const f32x2 w = xpair(st[k]);
            st[k] = cfma(mb, w, cmul(ma, st[k]));
        }
    }
    {   const f32x2 M00 = mats[base + 4], M01 = mats[base + 5],
                    M10 = mats[base + 6], M11 = mats[base + 7];
        ROTP(0, 4) ROTP(1, 5) ROTP(2, 6) ROTP(3, 7)
    }
    {   const f32x2 M00 = mats[base + 8], M01 = mats[base + 9],
                    M10 = mats[base + 10], M11 = mats[base + 11];
        ROTP(0, 2) ROTP(1, 3) ROTP(4, 6) ROTP(5, 7)
    }
    {   const f32x2 M00 = mats[base + 12], M01 = mats[base + 13],
                    M10 = mats[base + 14], M11 = mats[base + 15];
        ROTP(0, 1) ROTP(2, 3) ROTP(4, 5) ROTP(6, 7)
    }
}

__device__ __forceinline__ void entangle(f32x2* st, const f32x2* __restrict__ mats,
                                         int ic, int u, bool hi) {
    rot_layer(st, mats, (ic * 2 + 0) * 16, u);
    cswap_local<4>(st, hi);
    SWAPV(st[4], st[6]) SWAPV(st[5], st[7])
    SWAPV(st[2], st[3]) SWAPV(st[6], st[7])
    cx0<1>(st);
    rot_layer(st, mats, (ic * 2 + 1) * 16, u);
    cswap_local<2>(st, hi);
    SWAPV(st[4], st[5]) SWAPV(st[6], st[7])
    cx0<2>(st);
    SWAPV(st[1], st[5]) SWAPV(st[3], st[7])
}

// ---- kernel A: 24 Rot matrices -> d_ws (one wave, runs once per launch) ----
__global__ void prep_mats(const float* __restrict__ w, float* __restrict__ ws) {
    const int t = threadIdx.x;
    if (t < 24) {
        const float phi = w[t * 3 + 0], th = w[t * 3 + 1], om = w[t * 3 + 2];
        float sth, cth; sincosf(0.5f * th, &sth, &cth);
        float sa, ca;   sincosf(0.5f * (phi + om), &sa, &ca);
        float sb, cb;   sincosf(0.5f * (phi - om), &sb, &cb);
        f32x2* m = (f32x2*)ws + t * 4;
        m[0] = { cth * ca, -cth * sa};   // m00
        m[1] = {-sth * cb, -sth * sb};   // m01
        m[2] = { sth * cb, -sth * sb};   // m10
        m[3] = { cth * ca,  cth * sa};   // m11
    }
}

__global__ __launch_bounds__(256) void qconv_kernel(const float* __restrict__ x,
                                                    const f32x2* __restrict__ mats,
                                                    float* __restrict__ out) {
    const int gid = blockIdx.x * 256 + threadIdx.x;   // 2 lanes per pixel
    const int u = gid & 1;
    const bool hi = (u != 0);
    const int pix = gid >> 1;
    const int b = pix >> 14, rem = pix & 16383, i = rem >> 7, j = rem & 127;
    const float* xb = x + ((size_t)(b * 3) << 14);

    f32x2 st[8];

    // channel 0: Mottonen on |0> == direct normalization
    float a0[9]; load9(a0, xb, i, j);
    {
        float s2 = 0.f;
#pragma unroll
        for (int k = 0; k < 9; ++k) s2 += a0[k] * a0[k];
        const float rs = rsq(s2 + 7e-4f);
#pragma unroll
        for (int k = 0; k < 8; ++k) {
            const float ak = hi ? (k == 0 ? a0[8] : 0.01f) : a0[k];
            st[k].x = ak * rs; st[k].y = 0.f;
        }
    }
    float a1[9]; load9(a1, xb + (1 << 14), i, j);   // prefetch ch1
    entangle(st, mats, 0, u, hi);

    cascade(st, a1, hi);
    float a2[9]; load9(a2, xb + (2 << 14), i, j);   // prefetch ch2
    entangle(st, mats, 1, u, hi);

    cascade(st, a2, hi);
    entangle(st, mats, 2, u, hi);

    if (!hi) {
        float* ob = out + ((size_t)b << 17) + (i << 7) + j;
#pragma unroll
        for (int k = 0; k < 8; ++k) {
            const float pr = (st[k].x * st[k].x + st[k].y * st[k].y) * 8.f;
            ob[(size_t)k << 14] = fminf(pr, 1.f);
        }
    }
}

}  // namespace

extern "C" void kernel_launch(void* const* d_in, const int* in_sizes, int n_in,
                              void* d_out, int out_size, void* d_ws, size_t ws_size,
                              hipStream_t stream) {
    const float* x = (const float*)d_in[0];        // (4,3,128,128) f32
    const float* w = (const float*)d_in[1];        // (3,2,4,3) f32
    float* out = (float*)d_out;                    // (4,8,128,128) f32

    prep_mats<<<1, 64, 0, stream>>>(w, (float*)d_ws);
    const int total = 4 * 128 * 128 * 2;           // 2 threads per pixel
    qconv_kernel<<<total / 256, 256, 0, stream>>>(x, (const f32x2*)d_ws, out);
}

// Round 5
// 14.376 us; speedup vs baseline: 1.3209x; 1.3209x over previous
//
#include <hip/hip_runtime.h>
#include <math.h>

namespace {

typedef __attribute__((ext_vector_type(2))) float f32x2;

constexpr int H = 128, W = 128;

// ---------- packed fp32 (VOP3P) with op_sel scalar-broadcast ----------
__device__ __forceinline__ f32x2 pk_mul_x(f32x2 a, f32x2 b) {
    f32x2 d; asm("v_pk_mul_f32 %0, %1, %2 op_sel:[0,0] op_sel_hi:[0,1]"
                 : "=v"(d) : "v"(a), "v"(b)); return d;
}
__device__ __forceinline__ f32x2 pk_fma_x(f32x2 a, f32x2 b, f32x2 c) {
    f32x2 d; asm("v_pk_fma_f32 %0, %1, %2, %3 op_sel:[0,0,0] op_sel_hi:[0,1,1]"
                 : "=v"(d) : "v"(a), "v"(b), "v"(c)); return d;
}
__device__ __forceinline__ f32x2 pk_fma_y(f32x2 a, f32x2 b, f32x2 c) {
    f32x2 d; asm("v_pk_fma_f32 %0, %1, %2, %3 op_sel:[1,0,0] op_sel_hi:[1,1,1]"
                 : "=v"(d) : "v"(a), "v"(b), "v"(c)); return d;
}
__device__ __forceinline__ f32x2 pk_fnma_y(f32x2 a, f32x2 b, f32x2 c) {
    f32x2 d; asm("v_pk_fma_f32 %0, %1, %2, %3 op_sel:[1,0,0] op_sel_hi:[1,1,1] neg_lo:[1,0,0] neg_hi:[1,0,0]"
                 : "=v"(d) : "v"(a), "v"(b), "v"(c)); return d;
}
// d = c + a.y * (i*b)
__device__ __forceinline__ f32x2 pk_fma_im(f32x2 a, f32x2 b, f32x2 c) {
    f32x2 d; asm("v_pk_fma_f32 %0, %1, %2, %3 op_sel:[1,1,0] op_sel_hi:[1,0,1] neg_lo:[0,1,0]"
                 : "=v"(d) : "v"(a), "v"(b), "v"(c)); return d;
}
// b-broadcast variants: d = a * b.x (+ c)
__device__ __forceinline__ f32x2 pk_mul_b0(f32x2 a, f32x2 b) {
    f32x2 d; asm("v_pk_mul_f32 %0, %1, %2 op_sel:[0,0] op_sel_hi:[1,0]"
                 : "=v"(d) : "v"(a), "v"(b)); return d;
}
__device__ __forceinline__ f32x2 pk_fma_b0(f32x2 a, f32x2 b, f32x2 c) {
    f32x2 d; asm("v_pk_fma_f32 %0, %1, %2, %3 op_sel:[0,0,0] op_sel_hi:[1,0,1]"
                 : "=v"(d) : "v"(a), "v"(b), "v"(c)); return d;
}
__device__ __forceinline__ f32x2 cmul(f32x2 m, f32x2 v) { return pk_fma_im(m, v, pk_mul_x(m, v)); }
__device__ __forceinline__ f32x2 cfma(f32x2 m, f32x2 v, f32x2 a) { return pk_fma_im(m, v, pk_fma_x(m, v, a)); }

// ---------- partner-lane exchange (lanes 2m <-> 2m+1), DPP quad_perm [1,0,3,2] ----------
__device__ __forceinline__ float dpp1(float v) {
    return __int_as_float(__builtin_amdgcn_update_dpp(0, __float_as_int(v), 0xB1, 0xF, 0xF, true));
}
__device__ __forceinline__ f32x2 xpair(f32x2 v) { f32x2 r; r.x = dpp1(v.x); r.y = dpp1(v.y); return r; }

__device__ __forceinline__ float rsq(float x) { return __builtin_amdgcn_rsqf(x); }

#define RYP(i0, i1) { const f32x2 v0 = st[i0], v1 = st[i1];                         \
    st[i0] = pk_fnma_y(cs, v1, pk_mul_x(cs, v0));                                    \
    st[i1] = pk_fma_y(cs, v0, pk_mul_x(cs, v1)); }

#define ROTP(i0, i1) { const f32x2 v0 = st[i0], v1 = st[i1];                        \
    st[i0] = cfma(M01, v1, cmul(M00, v0));                                           \
    st[i1] = cfma(M11, v1, cmul(M10, v0)); }

#define SWAPV(a, b) { const f32x2 _t = (a); (a) = (b); (b) = _t; }

template <int M>
__device__ __forceinline__ void cswap_local(f32x2* st, bool hi) {
#pragma unroll
    for (int k = 0; k < 8; ++k) {
        if ((k & M) == 0) {
            const f32x2 A = st[k], B = st[k | M];
            st[k] = hi ? B : A;
            st[k | M] = hi ? A : B;
        }
    }
}
template <int M>
__device__ __forceinline__ void cx0(f32x2* st) {
#pragma unroll
    for (int k = 0; k < 8; ++k)
        if (k & M) st[k] = xpair(st[k]);
}

__device__ __forceinline__ void load9(float* a, const float* __restrict__ xc,
                                      int i, int j, bool interior) {
    if (interior) {
        const float* c = xc + ((i - 1) << 7) + (j - 1);
#pragma unroll
        for (int di = 0; di < 3; ++di)
#pragma unroll
            for (int dj = 0; dj < 3; ++dj)
                a[di * 3 + dj] = c[(di << 7) + dj] + 0.01f;
    } else {
#pragma unroll
        for (int di = 0; di < 3; ++di) {
#pragma unroll
            for (int dj = 0; dj < 3; ++dj) {
                const int y = i + di - 1, z = j + dj - 1;
                float v = 0.f;
                if ((unsigned)y < (unsigned)H && (unsigned)z < (unsigned)W) v = xc[(y << 7) + z];
                a[di * 3 + dj] = v + 0.01f;
            }
        }
    }
}

// Mottonen cascade, split form; all (c,s) from per-node rsq, leaves use a_k directly.
__device__ __forceinline__ void cascade(f32x2* st, const float* a, bool hi) {
    float p[9];
#pragma unroll
    for (int k = 0; k < 9; ++k) p[k] = a[k] * a[k];
    const float t10 = p[0] + p[1], t11 = p[2] + p[3], t12 = p[4] + p[5], t13 = p[6] + p[7];
    const float t14 = p[8] + 1e-4f;
    const float t20 = t10 + t11, t21 = t12 + t13, t22 = t14 + 2e-4f;
    const float t30 = t20 + t21, t31 = t22 + 4e-4f;

    const float r30 = rsq(t30), r31 = rsq(t31);
    const float r20 = rsq(t20), r21 = rsq(t21), r22 = rsq(t22);
    const float r10 = rsq(t10), r11 = rsq(t11), r12 = rsq(t12), r13 = rsq(t13), r14 = rsq(t14);

    constexpr float RH = 0.70710678118654752f;

    {   // q0 (cross)
        const float R = rsq(t30 + t31);
        f32x2 cs0; cs0.x = t30 * r30 * R; cs0.y = t31 * r31 * R;
        cs0.y = hi ? cs0.y : -cs0.y;
#pragma unroll
        for (int k = 0; k < 8; ++k) {
            const f32x2 w = xpair(st[k]);
            st[k] = pk_fma_y(cs0, w, pk_mul_x(cs0, st[k]));
        }
    }
    {   // q1 (mask 4)
        const float rp = hi ? r31 : r30;
        f32x2 cs; cs.x = (hi ? t22 * r22 : t20 * r20) * rp;
        cs.y = (hi ? 2e-2f : t21 * r21) * rp;
        RYP(0, 4) RYP(1, 5) RYP(2, 6) RYP(3, 7)
    }
    {   // q2 slots 0-3
        const float rp = hi ? r22 : r20;
        f32x2 cs; cs.x = (hi ? t14 * r14 : t10 * r10) * rp;
        cs.y = (hi ? 1.41421356e-2f : t11 * r11) * rp;
        RYP(0, 2) RYP(1, 3)
    }
    {   // q2 slots 4-7
        f32x2 cs; cs.x = hi ? RH : t12 * r12 * r21;
        cs.y = hi ? RH : t13 * r13 * r21;
        RYP(4, 6) RYP(5, 7)
    }
    // q3 leaves
    { f32x2 cs; cs.x = (hi ? a[8] : a[0]) * (hi ? r14 : r10);
      cs.y = (hi ? 0.01f : a[1]) * (hi ? r14 : r10); RYP(0, 1) }
    { f32x2 cs; cs.x = hi ? RH : a[2] * r11; cs.y = hi ? RH : a[3] * r11; RYP(2, 3) }
    { f32x2 cs; cs.x = hi ? RH : a[4] * r12; cs.y = hi ? RH : a[5] * r12; RYP(4, 5) }
    { f32x2 cs; cs.x = hi ? RH : a[6] * r13; cs.y = hi ? RH : a[7] * r13; RYP(6, 7) }
}

// wires 1-3 of a rot layer (local, complex)
__device__ __forceinline__ void rot_wires123(f32x2* st, const f32x2* __restrict__ mats, int base) {
    {   const f32x2 M00 = mats[base + 4], M01 = mats[base + 5],
                    M10 = mats[base + 6], M11 = mats[base + 7];
        ROTP(0, 4) ROTP(1, 5) ROTP(2, 6) ROTP(3, 7)
    }
    {   const f32x2 M00 = mats[base + 8], M01 = mats[base + 9],
                    M10 = mats[base + 10], M11 = mats[base + 11];
        ROTP(0, 2) ROTP(1, 3) ROTP(4, 6) ROTP(5, 7)
    }
    {   const f32x2 M00 = mats[base + 12], M01 = mats[base + 13],
                    M10 = mats[base + 14], M11 = mats[base + 15];
        ROTP(0, 1) ROTP(2, 3) ROTP(4, 5) ROTP(6, 7)
    }
}

__device__ __forceinline__ void rot_layer(f32x2* st, const f32x2* __restrict__ mats,
                                          int base, int u) {
    {   // wire 0 (cross): A: o = m00*v + m01*w ; B: o = m11*v + m10*w
        const f32x2 ma = mats[base + 3 * u], mb = mats[base + 1 + u];
#pragma unroll
        for (int k = 0; k < 8; ++k) {
            const f32x2 w = xpair(st[k]);
            st[k] = cfma(mb, w, cmul(ma, st[k]));
        }
    }
    rot_wires123(st, mats, base);
}

// first rot layer of entangle 0: incoming state is REAL and both lanes hold all
// of it locally (lo owns a0[0..8]; hi slots are 0.01 consts) -> no DPP on wire 0.
__device__ __forceinline__ void rot_layer_first(f32x2* st, const float* a0,
                                                const f32x2* __restrict__ mats,
                                                int u, bool hi) {
    const f32x2 ma = mats[3 * u], mb = mats[1 + u];
#pragma unroll
    for (int k = 0; k < 8; ++k) {
        const float dval = (k == 0) ? a0[8] : 0.01f;   // hi-lane slot value
        const float v = hi ? dval : a0[k];
        const float w = hi ? a0[k] : dval;
        const f32x2 vB = {v, v}, wB = {w, w};
        st[k] = pk_fma_b0(mb, wB, pk_mul_b0(ma, vB));
    }
    rot_wires123(st, mats, 0);
}

// after layer-0 rots: layer-0 cnots, layer-1 rots, layer-1 cnots
__device__ __forceinline__ void entangle_rest(f32x2* st, const f32x2* __restrict__ mats,
                                              int ic, int u, bool hi) {
    cswap_local<4>(st, hi);
    SWAPV(st[4], st[6]) SWAPV(st[5], st[7])
    SWAPV(st[2], st[3]) SWAPV(st[6], st[7])
    cx0<1>(st);
    rot_layer(st, mats, (ic * 2 + 1) * 16, u);
    cswap_local<2>(st, hi);
    SWAPV(st[4], st[5]) SWAPV(st[6], st[7])
    cx0<2>(st);
    SWAPV(st[1], st[5]) SWAPV(st[3], st[7])
}

__global__ __launch_bounds__(256) void qconv_kernel(const float* __restrict__ x,
                                                    const float* __restrict__ w,
                                                    float* __restrict__ out) {
    // ---- prologue: 24 Rot matrices, sincos spread over 72 threads ----
    __shared__ f32x2 mats[24 * 4];
    __shared__ float ang[72][2];
    const int t = threadIdx.x;
    if (t < 72) {
        const int q = t / 3, r = t - q * 3;
        const float phi = w[q * 3 + 0], th = w[q * 3 + 1], om = w[q * 3 + 2];
        const float angle = (r == 0) ? 0.5f * th : (r == 1 ? 0.5f * (phi + om) : 0.5f * (phi - om));
        float s, c; sincosf(angle, &s, &c);
        ang[t][0] = s; ang[t][1] = c;
    }
    __syncthreads();
    if (t < 24) {
        const float sth = ang[t * 3][0],     cth = ang[t * 3][1];
        const float sa  = ang[t * 3 + 1][0], ca  = ang[t * 3 + 1][1];
        const float sb  = ang[t * 3 + 2][0], cb  = ang[t * 3 + 2][1];
        f32x2* m = &mats[t * 4];
        m[0] = { cth * ca, -cth * sa};   // m00
        m[1] = {-sth * cb, -sth * sb};   // m01
        m[2] = { sth * cb, -sth * sb};   // m10
        m[3] = { cth * ca,  cth * sa};   // m11
    }
    __syncthreads();

    const int gid = blockIdx.x * 256 + t;   // 2 lanes per pixel
    const int u = gid & 1;
    const bool hi = (u != 0);
    const int pix = gid >> 1;
    const int b = pix >> 14, rem = pix & 16383, i = rem >> 7, j = rem & 127;
    const bool interior = ((unsigned)(i - 1) < 126u) & ((unsigned)(j - 1) < 126u);
    const float* xb = x + ((size_t)(b * 3) << 14);

    // channel 0 amplitudes (raw; normalization deferred to output scale)
    float a0[9]; load9(a0, xb, i, j, interior);
    float s2 = 7e-4f;   // 7 padding slots of 0.01^2
#pragma unroll
    for (int k = 0; k < 9; ++k) s2 += a0[k] * a0[k];
    const float sc = 8.f * __builtin_amdgcn_rcpf(s2);

    f32x2 st[8];
    float a1[9]; load9(a1, xb + (1 << 14), i, j, interior);   // prefetch ch1

    // entangle 0 (real-state first layer)
    rot_layer_first(st, a0, mats, u, hi);
    entangle_rest(st, mats, 0, u, hi);

    cascade(st, a1, hi);
    float a2[9]; load9(a2, xb + (2 << 14), i, j, interior);   // prefetch ch2
    rot_layer(st, mats, 32, u);
    entangle_rest(st, mats, 1, u, hi);

    cascade(st, a2, hi);
    rot_layer(st, mats, 64, u);
    entangle_rest(st, mats, 2, u, hi);

    if (!hi) {
        float* ob = out + ((size_t)b << 17) + (i << 7) + j;
#pragma unroll
        for (int k = 0; k < 8; ++k) {
            const float pr = (st[k].x * st[k].x + st[k].y * st[k].y) * sc;
            ob[(size_t)k << 14] = fminf(pr, 1.f);
        }
    }
}

}  // namespace

extern "C" void kernel_launch(void* const* d_in, const int* in_sizes, int n_in,
                              void* d_out, int out_size, void* d_ws, size_t ws_size,
                              hipStream_t stream) {
    const float* x = (const float*)d_in[0];        // (4,3,128,128) f32
    const float* w = (const float*)d_in[1];        // (3,2,4,3) f32
    float* out = (float*)d_out;                    // (4,8,128,128) f32
    const int total = 4 * 128 * 128 * 2;           // 2 threads per pixel
    qconv_kernel<<<total / 256, 256, 0, stream>>>(x, w, out);
}

// Round 6
// 13.739 us; speedup vs baseline: 1.3822x; 1.0464x over previous
//
#include <hip/hip_runtime.h>

namespace {

typedef __attribute__((ext_vector_type(2))) float f32x2;

constexpr int H = 128, W = 128;

// ---------- packed fp32 (VOP3P) with op_sel scalar-broadcast ----------
__device__ __forceinline__ f32x2 pk_mul_x(f32x2 a, f32x2 b) {
    f32x2 d; asm("v_pk_mul_f32 %0, %1, %2 op_sel:[0,0] op_sel_hi:[0,1]"
                 : "=v"(d) : "v"(a), "v"(b)); return d;
}
__device__ __forceinline__ f32x2 pk_fma_x(f32x2 a, f32x2 b, f32x2 c) {
    f32x2 d; asm("v_pk_fma_f32 %0, %1, %2, %3 op_sel:[0,0,0] op_sel_hi:[0,1,1]"
                 : "=v"(d) : "v"(a), "v"(b), "v"(c)); return d;
}
__device__ __forceinline__ f32x2 pk_fma_y(f32x2 a, f32x2 b, f32x2 c) {
    f32x2 d; asm("v_pk_fma_f32 %0, %1, %2, %3 op_sel:[1,0,0] op_sel_hi:[1,1,1]"
                 : "=v"(d) : "v"(a), "v"(b), "v"(c)); return d;
}
__device__ __forceinline__ f32x2 pk_fnma_y(f32x2 a, f32x2 b, f32x2 c) {
    f32x2 d; asm("v_pk_fma_f32 %0, %1, %2, %3 op_sel:[1,0,0] op_sel_hi:[1,1,1] neg_lo:[1,0,0] neg_hi:[1,0,0]"
                 : "=v"(d) : "v"(a), "v"(b), "v"(c)); return d;
}
// d = c + a.y * (i*b)
__device__ __forceinline__ f32x2 pk_fma_im(f32x2 a, f32x2 b, f32x2 c) {
    f32x2 d; asm("v_pk_fma_f32 %0, %1, %2, %3 op_sel:[1,1,0] op_sel_hi:[1,0,1] neg_lo:[0,1,0]"
                 : "=v"(d) : "v"(a), "v"(b), "v"(c)); return d;
}
// b-broadcast variants: d = a * b.x (+ c)
__device__ __forceinline__ f32x2 pk_mul_b0(f32x2 a, f32x2 b) {
    f32x2 d; asm("v_pk_mul_f32 %0, %1, %2 op_sel:[0,0] op_sel_hi:[1,0]"
                 : "=v"(d) : "v"(a), "v"(b)); return d;
}
__device__ __forceinline__ f32x2 pk_fma_b0(f32x2 a, f32x2 b, f32x2 c) {
    f32x2 d; asm("v_pk_fma_f32 %0, %1, %2, %3 op_sel:[0,0,0] op_sel_hi:[1,0,1]"
                 : "=v"(d) : "v"(a), "v"(b), "v"(c)); return d;
}
__device__ __forceinline__ f32x2 cmul(f32x2 m, f32x2 v) { return pk_fma_im(m, v, pk_mul_x(m, v)); }
__device__ __forceinline__ f32x2 cfma(f32x2 m, f32x2 v, f32x2 a) { return pk_fma_im(m, v, pk_fma_x(m, v, a)); }

// ---------- partner-lane exchange (lanes 2m <-> 2m+1), DPP quad_perm [1,0,3,2] ----------
__device__ __forceinline__ float dpp1(float v) {
    return __int_as_float(__builtin_amdgcn_update_dpp(0, __float_as_int(v), 0xB1, 0xF, 0xF, true));
}
__device__ __forceinline__ f32x2 xpair(f32x2 v) { f32x2 r; r.x = dpp1(v.x); r.y = dpp1(v.y); return r; }

__device__ __forceinline__ float rsq(float x) { return __builtin_amdgcn_rsqf(x); }

#define RYP(i0, i1) { const f32x2 v0 = st[i0], v1 = st[i1];                         \
    st[i0] = pk_fnma_y(cs, v1, pk_mul_x(cs, v0));                                    \
    st[i1] = pk_fma_y(cs, v0, pk_mul_x(cs, v1)); }

#define ROTP(i0, i1) { const f32x2 v0 = st[i0], v1 = st[i1];                        \
    st[i0] = cfma(M01, v1, cmul(M00, v0));                                           \
    st[i1] = cfma(M11, v1, cmul(M10, v0)); }

#define SWAPV(a, b) { const f32x2 _t = (a); (a) = (b); (b) = _t; }

template <int M>
__device__ __forceinline__ void cswap_local(f32x2* st, bool hi) {
#pragma unroll
    for (int k = 0; k < 8; ++k) {
        if ((k & M) == 0) {
            const f32x2 A = st[k], B = st[k | M];
            st[k] = hi ? B : A;
            st[k | M] = hi ? A : B;
        }
    }
}
template <int M>
__device__ __forceinline__ void cx0(f32x2* st) {
#pragma unroll
    for (int k = 0; k < 8; ++k)
        if (k & M) st[k] = xpair(st[k]);
}

__device__ __forceinline__ void load9(float* a, const float* __restrict__ xc,
                                      int i, int j, bool interior) {
    if (interior) {
        const float* c = xc + ((i - 1) << 7) + (j - 1);
#pragma unroll
        for (int di = 0; di < 3; ++di)
#pragma unroll
            for (int dj = 0; dj < 3; ++dj)
                a[di * 3 + dj] = c[(di << 7) + dj] + 0.01f;
    } else {
#pragma unroll
        for (int di = 0; di < 3; ++di) {
#pragma unroll
            for (int dj = 0; dj < 3; ++dj) {
                const int y = i + di - 1, z = j + dj - 1;
                float v = 0.f;
                if ((unsigned)y < (unsigned)H && (unsigned)z < (unsigned)W) v = xc[(y << 7) + z];
                a[di * 3 + dj] = v + 0.01f;
            }
        }
    }
}

// Mottonen cascade, split form; all (c,s) from per-node rsq, leaves use a_k directly.
__device__ __forceinline__ void cascade(f32x2* st, const float* a, bool hi) {
    float p[9];
#pragma unroll
    for (int k = 0; k < 9; ++k) p[k] = a[k] * a[k];
    const float t10 = p[0] + p[1], t11 = p[2] + p[3], t12 = p[4] + p[5], t13 = p[6] + p[7];
    const float t14 = p[8] + 1e-4f;
    const float t20 = t10 + t11, t21 = t12 + t13, t22 = t14 + 2e-4f;
    const float t30 = t20 + t21, t31 = t22 + 4e-4f;

    const float r30 = rsq(t30), r31 = rsq(t31);
    const float r20 = rsq(t20), r21 = rsq(t21), r22 = rsq(t22);
    const float r10 = rsq(t10), r11 = rsq(t11), r12 = rsq(t12), r13 = rsq(t13), r14 = rsq(t14);

    constexpr float RH = 0.70710678118654752f;

    {   // q0 (cross)
        const float R = rsq(t30 + t31);
        f32x2 cs0; cs0.x = t30 * r30 * R; cs0.y = t31 * r31 * R;
        cs0.y = hi ? cs0.y : -cs0.y;
#pragma unroll
        for (int k = 0; k < 8; ++k) {
            const f32x2 w = xpair(st[k]);
            st[k] = pk_fma_y(cs0, w, pk_mul_x(cs0, st[k]));
        }
    }
    {   // q1 (mask 4)
        const float rp = hi ? r31 : r30;
        f32x2 cs; cs.x = (hi ? t22 * r22 : t20 * r20) * rp;
        cs.y = (hi ? 2e-2f : t21 * r21) * rp;
        RYP(0, 4) RYP(1, 5) RYP(2, 6) RYP(3, 7)
    }
    {   // q2 slots 0-3
        const float rp = hi ? r22 : r20;
        f32x2 cs; cs.x = (hi ? t14 * r14 : t10 * r10) * rp;
        cs.y = (hi ? 1.41421356e-2f : t11 * r11) * rp;
        RYP(0, 2) RYP(1, 3)
    }
    {   // q2 slots 4-7
        f32x2 cs; cs.x = hi ? RH : t12 * r12 * r21;
        cs.y = hi ? RH : t13 * r13 * r21;
        RYP(4, 6) RYP(5, 7)
    }
    // q3 leaves
    { f32x2 cs; cs.x = (hi ? a[8] : a[0]) * (hi ? r14 : r10);
      cs.y = (hi ? 0.01f : a[1]) * (hi ? r14 : r10); RYP(0, 1) }
    { f32x2 cs; cs.x = hi ? RH : a[2] * r11; cs.y = hi ? RH : a[3] * r11; RYP(2, 3) }
    { f32x2 cs; cs.x = hi ? RH : a[4] * r12; cs.y = hi ? RH : a[5] * r12; RYP(4, 5) }
    { f32x2 cs; cs.x = hi ? RH : a[6] * r13; cs.y = hi ? RH : a[7] * r13; RYP(6, 7) }
}

// wires 1-3 of a rot layer (local, complex)
__device__ __forceinline__ void rot_wires123(f32x2* st, const f32x2* __restrict__ mats, int base) {
    {   const f32x2 M00 = mats[base + 4], M01 = mats[base + 5],
                    M10 = mats[base + 6], M11 = mats[base + 7];
        ROTP(0, 4) ROTP(1, 5) ROTP(2, 6) ROTP(3, 7)
    }
    {   const f32x2 M00 = mats[base + 8], M01 = mats[base + 9],
                    M10 = mats[base + 10], M11 = mats[base + 11];
        ROTP(0, 2) ROTP(1, 3) ROTP(4, 6) ROTP(5, 7)
    }
    {   const f32x2 M00 = mats[base + 12], M01 = mats[base + 13],
                    M10 = mats[base + 14], M11 = mats[base + 15];
        ROTP(0, 1) ROTP(2, 3) ROTP(4, 5) ROTP(6, 7)
    }
}

__device__ __forceinline__ void rot_layer(f32x2* st, const f32x2* __restrict__ mats,
                                          int base, int u) {
    {   // wire 0 (cross): A: o = m00*v + m01*w ; B: o = m11*v + m10*w
        const f32x2 ma = mats[base + 3 * u], mb = mats[base + 1 + u];
#pragma unroll
        for (int k = 0; k < 8; ++k) {
            const f32x2 w = xpair(st[k]);
            st[k] = cfma(mb, w, cmul(ma, st[k]));
        }
    }
    rot_wires123(st, mats, base);
}

// first rot layer of entangle 0: incoming state is REAL and both lanes hold all
// of it locally (lo owns a0[0..8]; hi slots are 0.01 consts) -> no DPP on wire 0.
__device__ __forceinline__ void rot_layer_first(f32x2* st, const float* a0,
                                                const f32x2* __restrict__ mats,
                                                int u, bool hi) {
    const f32x2 ma = mats[3 * u], mb = mats[1 + u];
#pragma unroll
    for (int k = 0; k < 8; ++k) {
        const float dval = (k == 0) ? a0[8] : 0.01f;   // hi-lane slot value
        const float v = hi ? dval : a0[k];
        const float w = hi ? a0[k] : dval;
        const f32x2 vB = {v, v}, wB = {w, w};
        st[k] = pk_fma_b0(mb, wB, pk_mul_b0(ma, vB));
    }
    rot_wires123(st, mats, 0);
}

// layer-0 CNOTs (range 1): (0,1) (1,2) (2,3) (3,0)
__device__ __forceinline__ void cnots_l0(f32x2* st, bool hi) {
    cswap_local<4>(st, hi);
    SWAPV(st[4], st[6]) SWAPV(st[5], st[7])
    SWAPV(st[2], st[3]) SWAPV(st[6], st[7])
    cx0<1>(st);
}

// full entangle tail for mid-circuit channels (layer-0 cnots, layer-1 rots, layer-1 cnots)
__device__ __forceinline__ void entangle_rest(f32x2* st, const f32x2* __restrict__ mats,
                                              int ic, int u, bool hi) {
    cnots_l0(st, hi);
    rot_layer(st, mats, (ic * 2 + 1) * 16, u);
    cswap_local<2>(st, hi);
    SWAPV(st[4], st[5]) SWAPV(st[6], st[7])
    cx0<2>(st);
    SWAPV(st[1], st[5]) SWAPV(st[3], st[7])
}

__global__ __launch_bounds__(512) void qconv_kernel(const float* __restrict__ x,
                                                    const float* __restrict__ w,
                                                    float* __restrict__ out) {
    // ---- prologue: 24 Rot matrices via raw v_sin/v_cos (angles < 1 rad,
    //      no range reduction needed; v_sin takes revolutions) ----
    __shared__ f32x2 mats[24 * 4];
    const int t = threadIdx.x;
    if (t < 24) {
        const float phi = w[t * 3 + 0], th = w[t * 3 + 1], om = w[t * 3 + 2];
        constexpr float R2PI = 0.15915494309189535f;  // 1/(2*pi)
        const float v0 = 0.5f * th * R2PI;
        const float v1 = 0.5f * (phi + om) * R2PI;
        const float v2 = 0.5f * (phi - om) * R2PI;
        const float sth = __builtin_amdgcn_sinf(v0), cth = __builtin_amdgcn_cosf(v0);
        const float sa  = __builtin_amdgcn_sinf(v1), ca  = __builtin_amdgcn_cosf(v1);
        const float sb  = __builtin_amdgcn_sinf(v2), cb  = __builtin_amdgcn_cosf(v2);
        f32x2* m = &mats[t * 4];
        m[0] = { cth * ca, -cth * sa};   // m00
        m[1] = {-sth * cb, -sth * sb};   // m01
        m[2] = { sth * cb, -sth * sb};   // m10
        m[3] = { cth * ca,  cth * sa};   // m11
    }
    __syncthreads();

    const int gid = blockIdx.x * 512 + t;   // 2 lanes per pixel
    const int u = gid & 1;
    const bool hi = (u != 0);
    const int pix = gid >> 1;
    const int b = pix >> 14, rem = pix & 16383, i = rem >> 7, j = rem & 127;
    const bool interior = ((unsigned)(i - 1) < 126u) & ((unsigned)(j - 1) < 126u);
    const float* xb = x + ((size_t)(b * 3) << 14);

    // channel 0 amplitudes (raw; normalization deferred to output scale)
    float a0[9]; load9(a0, xb, i, j, interior);
    float s2 = 7e-4f;   // 7 padding slots of 0.01^2
#pragma unroll
    for (int k = 0; k < 9; ++k) s2 += a0[k] * a0[k];
    const float sc = 8.f * __builtin_amdgcn_rcpf(s2);

    f32x2 st[8];
    float a1[9]; load9(a1, xb + (1 << 14), i, j, interior);   // prefetch ch1

    // entangle 0 (real-state first layer)
    rot_layer_first(st, a0, mats, u, hi);
    entangle_rest(st, mats, 0, u, hi);

    cascade(st, a1, hi);
    float a2[9]; load9(a2, xb + (2 << 14), i, j, interior);   // prefetch ch2
    rot_layer(st, mats, 32, u);
    entangle_rest(st, mats, 1, u, hi);

    cascade(st, a2, hi);
    rot_layer(st, mats, 64, u);
    cnots_l0(st, hi);
    rot_layer(st, mats, 80, u);
    // final CNOT layer (0,2)(1,3)(2,0)(3,1) folded into the store map:
    // new[(p,q,r,s)] = old[(r^p, s^q, p, q)]  =>
    //   lane u stores planes {0,1,4,5} + 2u from registers {st0, st4, st5, st1}.
    {
        float* ob = out + ((size_t)b << 17) + (i << 7) + j;
        const int po = u << 1;
        const float pr0 = (st[0].x * st[0].x + st[0].y * st[0].y) * sc;
        const float pr1 = (st[4].x * st[4].x + st[4].y * st[4].y) * sc;
        const float pr4 = (st[5].x * st[5].x + st[5].y * st[5].y) * sc;
        const float pr5 = (st[1].x * st[1].x + st[1].y * st[1].y) * sc;
        ob[(size_t)(po + 0) << 14] = fminf(pr0, 1.f);
        ob[(size_t)(po + 1) << 14] = fminf(pr1, 1.f);
        ob[(size_t)(po + 4) << 14] = fminf(pr4, 1.f);
        ob[(size_t)(po + 5) << 14] = fminf(pr5, 1.f);
    }
}

}  // namespace

extern "C" void kernel_launch(void* const* d_in, const int* in_sizes, int n_in,
                              void* d_out, int out_size, void* d_ws, size_t ws_size,
                              hipStream_t stream) {
    const float* x = (const float*)d_in[0];        // (4,3,128,128) f32
    const float* w = (const float*)d_in[1];        // (3,2,4,3) f32
    float* out = (float*)d_out;                    // (4,8,128,128) f32
    const int total = 4 * 128 * 128 * 2;           // 2 threads per pixel
    qconv_kernel<<<total / 512, 512, 0, stream>>>(x, w, out);
}

// Round 7
// 13.726 us; speedup vs baseline: 1.3835x; 1.0009x over previous
//
#include <hip/hip_runtime.h>

namespace {

typedef __attribute__((ext_vector_type(2))) float f32x2;

constexpr int H = 128, W = 128;

// ---------- packed fp32 (VOP3P) with op_sel scalar-broadcast ----------
__device__ __forceinline__ f32x2 pk_mul_x(f32x2 a, f32x2 b) {
    f32x2 d; asm("v_pk_mul_f32 %0, %1, %2 op_sel:[0,0] op_sel_hi:[0,1]"
                 : "=v"(d) : "v"(a), "v"(b)); return d;
}
__device__ __forceinline__ f32x2 pk_fma_x(f32x2 a, f32x2 b, f32x2 c) {
    f32x2 d; asm("v_pk_fma_f32 %0, %1, %2, %3 op_sel:[0,0,0] op_sel_hi:[0,1,1]"
                 : "=v"(d) : "v"(a), "v"(b), "v"(c)); return d;
}
__device__ __forceinline__ f32x2 pk_fma_y(f32x2 a, f32x2 b, f32x2 c) {
    f32x2 d; asm("v_pk_fma_f32 %0, %1, %2, %3 op_sel:[1,0,0] op_sel_hi:[1,1,1]"
                 : "=v"(d) : "v"(a), "v"(b), "v"(c)); return d;
}
__device__ __forceinline__ f32x2 pk_fnma_y(f32x2 a, f32x2 b, f32x2 c) {
    f32x2 d; asm("v_pk_fma_f32 %0, %1, %2, %3 op_sel:[1,0,0] op_sel_hi:[1,1,1] neg_lo:[1,0,0] neg_hi:[1,0,0]"
                 : "=v"(d) : "v"(a), "v"(b), "v"(c)); return d;
}
// d = c + a.y * (i*b)
__device__ __forceinline__ f32x2 pk_fma_im(f32x2 a, f32x2 b, f32x2 c) {
    f32x2 d; asm("v_pk_fma_f32 %0, %1, %2, %3 op_sel:[1,1,0] op_sel_hi:[1,0,1] neg_lo:[0,1,0]"
                 : "=v"(d) : "v"(a), "v"(b), "v"(c)); return d;
}
// b-broadcast variants: d = a * b.x (+ c)
__device__ __forceinline__ f32x2 pk_mul_b0(f32x2 a, f32x2 b) {
    f32x2 d; asm("v_pk_mul_f32 %0, %1, %2 op_sel:[0,0] op_sel_hi:[1,0]"
                 : "=v"(d) : "v"(a), "v"(b)); return d;
}
__device__ __forceinline__ f32x2 pk_fma_b0(f32x2 a, f32x2 b, f32x2 c) {
    f32x2 d; asm("v_pk_fma_f32 %0, %1, %2, %3 op_sel:[0,0,0] op_sel_hi:[1,0,1]"
                 : "=v"(d) : "v"(a), "v"(b), "v"(c)); return d;
}
__device__ __forceinline__ f32x2 cmul(f32x2 m, f32x2 v) { return pk_fma_im(m, v, pk_mul_x(m, v)); }
__device__ __forceinline__ f32x2 cfma(f32x2 m, f32x2 v, f32x2 a) { return pk_fma_im(m, v, pk_fma_x(m, v, a)); }

// ---------- partner-lane exchange (lanes 2m <-> 2m+1), DPP quad_perm [1,0,3,2] ----------
__device__ __forceinline__ float dpp1(float v) {
    return __int_as_float(__builtin_amdgcn_update_dpp(0, __float_as_int(v), 0xB1, 0xF, 0xF, true));
}
__device__ __forceinline__ f32x2 xpair(f32x2 v) { f32x2 r; r.x = dpp1(v.x); r.y = dpp1(v.y); return r; }

__device__ __forceinline__ float rsq(float x) { return __builtin_amdgcn_rsqf(x); }

#define RYP(i0, i1) { const f32x2 v0 = st[i0], v1 = st[i1];                         \
    st[i0] = pk_fnma_y(cs, v1, pk_mul_x(cs, v0));                                    \
    st[i1] = pk_fma_y(cs, v0, pk_mul_x(cs, v1)); }

#define ROTP(i0, i1) { const f32x2 v0 = st[i0], v1 = st[i1];                        \
    st[i0] = cfma(M01, v1, cmul(M00, v0));                                           \
    st[i1] = cfma(M11, v1, cmul(M10, v0)); }

#define SWAPV(a, b) { const f32x2 _t = (a); (a) = (b); (b) = _t; }

template <int M>
__device__ __forceinline__ void cswap_local(f32x2* st, bool hi) {
#pragma unroll
    for (int k = 0; k < 8; ++k) {
        if ((k & M) == 0) {
            const f32x2 A = st[k], B = st[k | M];
            st[k] = hi ? B : A;
            st[k | M] = hi ? A : B;
        }
    }
}

__device__ __forceinline__ void load9(float* a, const float* __restrict__ xc,
                                      int i, int j, bool interior) {
    if (interior) {
        const float* c = xc + ((i - 1) << 7) + (j - 1);
#pragma unroll
        for (int di = 0; di < 3; ++di)
#pragma unroll
            for (int dj = 0; dj < 3; ++dj)
                a[di * 3 + dj] = c[(di << 7) + dj] + 0.01f;
    } else {
#pragma unroll
        for (int di = 0; di < 3; ++di) {
#pragma unroll
            for (int dj = 0; dj < 3; ++dj) {
                const int y = i + di - 1, z = j + dj - 1;
                float v = 0.f;
                if ((unsigned)y < (unsigned)H && (unsigned)z < (unsigned)W) v = xc[(y << 7) + z];
                a[di * 3 + dj] = v + 0.01f;
            }
        }
    }
}

// Mottonen cascade, split form. FM = deferred-exchange flag mask: slots with
// (k & FM) carry a pending cross-lane exchange from the previous cx0 (folded
// into q0's own DPP fetch by swapping operand roles).
template <int FM>
__device__ __forceinline__ void cascade(f32x2* st, const float* a, bool hi) {
    float p[9];
#pragma unroll
    for (int k = 0; k < 9; ++k) p[k] = a[k] * a[k];
    const float t10 = p[0] + p[1], t11 = p[2] + p[3], t12 = p[4] + p[5], t13 = p[6] + p[7];
    const float t14 = p[8] + 1e-4f;
    const float t20 = t10 + t11, t21 = t12 + t13, t22 = t14 + 2e-4f;
    const float t30 = t20 + t21, t31 = t22 + 4e-4f;

    const float r30 = rsq(t30), r31 = rsq(t31);
    const float r20 = rsq(t20), r21 = rsq(t21), r22 = rsq(t22);
    const float r10 = rsq(t10), r11 = rsq(t11), r12 = rsq(t12), r13 = rsq(t13), r14 = rsq(t14);

    constexpr float RH = 0.70710678118654752f;

    {   // q0 (cross, consumes deferred exchange on flagged slots)
        const float R = rsq(t30 + t31);
        f32x2 cs0; cs0.x = t30 * r30 * R; cs0.y = t31 * r31 * R;
        cs0.y = hi ? cs0.y : -cs0.y;
#pragma unroll
        for (int k = 0; k < 8; ++k) {
            const f32x2 pw = xpair(st[k]);
            const f32x2 v = (k & FM) ? pw : st[k];
            const f32x2 w = (k & FM) ? st[k] : pw;
            st[k] = pk_fma_y(cs0, w, pk_mul_x(cs0, v));
        }
    }
    {   // q1 (mask 4)
        const float rp = hi ? r31 : r30;
        f32x2 cs; cs.x = (hi ? t22 * r22 : t20 * r20) * rp;
        cs.y = (hi ? 2e-2f : t21 * r21) * rp;
        RYP(0, 4) RYP(1, 5) RYP(2, 6) RYP(3, 7)
    }
    {   // q2 slots 0-3
        const float rp = hi ? r22 : r20;
        f32x2 cs; cs.x = (hi ? t14 * r14 : t10 * r10) * rp;
        cs.y = (hi ? 1.41421356e-2f : t11 * r11) * rp;
        RYP(0, 2) RYP(1, 3)
    }
    {   // q2 slots 4-7
        f32x2 cs; cs.x = hi ? RH : t12 * r12 * r21;
        cs.y = hi ? RH : t13 * r13 * r21;
        RYP(4, 6) RYP(5, 7)
    }
    // q3 leaves
    { f32x2 cs; cs.x = (hi ? a[8] : a[0]) * (hi ? r14 : r10);
      cs.y = (hi ? 0.01f : a[1]) * (hi ? r14 : r10); RYP(0, 1) }
    { f32x2 cs; cs.x = hi ? RH : a[2] * r11; cs.y = hi ? RH : a[3] * r11; RYP(2, 3) }
    { f32x2 cs; cs.x = hi ? RH : a[4] * r12; cs.y = hi ? RH : a[5] * r12; RYP(4, 5) }
    { f32x2 cs; cs.x = hi ? RH : a[6] * r13; cs.y = hi ? RH : a[7] * r13; RYP(6, 7) }
}

// wires 1-3 of a rot layer (local, complex)
__device__ __forceinline__ void rot_wires123(f32x2* st, const f32x2* __restrict__ mats, int base) {
    {   const f32x2 M00 = mats[base + 4], M01 = mats[base + 5],
                    M10 = mats[base + 6], M11 = mats[base + 7];
        ROTP(0, 4) ROTP(1, 5) ROTP(2, 6) ROTP(3, 7)
    }
    {   const f32x2 M00 = mats[base + 8], M01 = mats[base + 9],
                    M10 = mats[base + 10], M11 = mats[base + 11];
        ROTP(0, 2) ROTP(1, 3) ROTP(4, 6) ROTP(5, 7)
    }
    {   const f32x2 M00 = mats[base + 12], M01 = mats[base + 13],
                    M10 = mats[base + 14], M11 = mats[base + 15];
        ROTP(0, 1) ROTP(2, 3) ROTP(4, 5) ROTP(6, 7)
    }
}

// rot layer; FM = deferred-exchange flags consumed by the wire-0 cross op.
template <int FM>
__device__ __forceinline__ void rot_layer_def(f32x2* st, const f32x2* __restrict__ mats,
                                              int base, int u) {
    const f32x2 ma = mats[base + 3 * u], mb = mats[base + 1 + u];
#pragma unroll
    for (int k = 0; k < 8; ++k) {
        const f32x2 pw = xpair(st[k]);
        const f32x2 v = (k & FM) ? pw : st[k];
        const f32x2 w = (k & FM) ? st[k] : pw;
        st[k] = cfma(mb, w, cmul(ma, v));
    }
    rot_wires123(st, mats, base);
}

// first rot layer of entangle 0: incoming state is REAL and both lanes hold all
// of it locally (lo owns a0[0..8]; hi slots are 0.01 consts) -> no DPP on wire 0.
__device__ __forceinline__ void rot_layer_first(f32x2* st, const float* a0,
                                                const f32x2* __restrict__ mats,
                                                int u, bool hi) {
    const f32x2 ma = mats[3 * u], mb = mats[1 + u];
#pragma unroll
    for (int k = 0; k < 8; ++k) {
        const float dval = (k == 0) ? a0[8] : 0.01f;   // hi-lane slot value
        const float v = hi ? dval : a0[k];
        const float w = hi ? a0[k] : dval;
        const f32x2 vB = {v, v}, wB = {w, w};
        st[k] = pk_fma_b0(mb, wB, pk_mul_b0(ma, vB));
    }
    rot_wires123(st, mats, 0);
}

// layer-0 CNOTs (range 1) minus the trailing cx0<1> (deferred to next wire-0 cross)
__device__ __forceinline__ void cnots_l0_nox(f32x2* st, bool hi) {
    cswap_local<4>(st, hi);
    SWAPV(st[4], st[6]) SWAPV(st[5], st[7])
    SWAPV(st[2], st[3]) SWAPV(st[6], st[7])
}

// entangle tail: l0-cnots (cx0<1> deferred), layer-1 rots (consume), l1-cnots
// (cx0<2> deferred to the next cascade's q0; flag set stays {k&2} through renames)
__device__ __forceinline__ void entangle_tail(f32x2* st, const f32x2* __restrict__ mats,
                                              int base2, int u, bool hi) {
    cnots_l0_nox(st, hi);
    rot_layer_def<1>(st, mats, base2, u);
    cswap_local<2>(st, hi);
    SWAPV(st[4], st[5]) SWAPV(st[6], st[7])
    SWAPV(st[1], st[5]) SWAPV(st[3], st[7])
}

__global__ __launch_bounds__(512) void qconv_kernel(const float* __restrict__ x,
                                                    const float* __restrict__ w,
                                                    float* __restrict__ out) {
    // ---- prologue: 24 Rot matrices via raw v_sin/v_cos (angles < 1 rad) ----
    __shared__ f32x2 mats[24 * 4];
    const int t = threadIdx.x;
    if (t < 24) {
        const float phi = w[t * 3 + 0], th = w[t * 3 + 1], om = w[t * 3 + 2];
        constexpr float R2PI = 0.15915494309189535f;  // 1/(2*pi)
        const float v0 = 0.5f * th * R2PI;
        const float v1 = 0.5f * (phi + om) * R2PI;
        const float v2 = 0.5f * (phi - om) * R2PI;
        const float sth = __builtin_amdgcn_sinf(v0), cth = __builtin_amdgcn_cosf(v0);
        const float sa  = __builtin_amdgcn_sinf(v1), ca  = __builtin_amdgcn_cosf(v1);
        const float sb  = __builtin_amdgcn_sinf(v2), cb  = __builtin_amdgcn_cosf(v2);
        f32x2* m = &mats[t * 4];
        m[0] = { cth * ca, -cth * sa};   // m00
        m[1] = {-sth * cb, -sth * sb};   // m01
        m[2] = { sth * cb, -sth * sb};   // m10
        m[3] = { cth * ca,  cth * sa};   // m11
    }

    const int gid = blockIdx.x * 512 + t;   // 2 lanes per pixel
    const int u = gid & 1;
    const bool hi = (u != 0);
    const int pix = gid >> 1;
    const int b = pix >> 14, rem = pix & 16383, i = rem >> 7, j = rem & 127;
    const bool interior = ((unsigned)(i - 1) < 126u) & ((unsigned)(j - 1) < 126u);
    const float* xb = x + ((size_t)(b * 3) << 14);

    // ---- issue ALL channel loads before the barrier (latency hidden behind it) ----
    float a0[9]; load9(a0, xb, i, j, interior);
    float a1[9]; load9(a1, xb + (1 << 14), i, j, interior);
    float a2[9]; load9(a2, xb + (2 << 14), i, j, interior);
    float s2 = 7e-4f;   // 7 padding slots of 0.01^2
#pragma unroll
    for (int k = 0; k < 9; ++k) s2 += a0[k] * a0[k];
    const float sc = 8.f * __builtin_amdgcn_rcpf(s2);

    __syncthreads();

    f32x2 st[8];

    // entangle 0 (real-state first layer; ch0 Mottonen == deferred normalization)
    rot_layer_first(st, a0, mats, u, hi);
    entangle_tail(st, mats, 16, u, hi);

    cascade<2>(st, a1, hi);
    rot_layer_def<0>(st, mats, 32, u);
    entangle_tail(st, mats, 48, u, hi);

    cascade<2>(st, a2, hi);
    rot_layer_def<0>(st, mats, 64, u);
    cnots_l0_nox(st, hi);
    rot_layer_def<1>(st, mats, 80, u);

    // final CNOT layer (0,2)(1,3)(2,0)(3,1) folded into the store map:
    // lane u stores planes {0,1,4,5} + 2u from registers {st0, st4, st5, st1}.
    {
        float* ob = out + ((size_t)b << 17) + (i << 7) + j;
        const int po = u << 1;
        const float pr0 = (st[0].x * st[0].x + st[0].y * st[0].y) * sc;
        const float pr1 = (st[4].x * st[4].x + st[4].y * st[4].y) * sc;
        const float pr4 = (st[5].x * st[5].x + st[5].y * st[5].y) * sc;
        const float pr5 = (st[1].x * st[1].x + st[1].y * st[1].y) * sc;
        ob[(size_t)(po + 0) << 14] = fminf(pr0, 1.f);
        ob[(size_t)(po + 1) << 14] = fminf(pr1, 1.f);
        ob[(size_t)(po + 4) << 14] = fminf(pr4, 1.f);
        ob[(size_t)(po + 5) << 14] = fminf(pr5, 1.f);
    }
}

}  // namespace

extern "C" void kernel_launch(void* const* d_in, const int* in_sizes, int n_in,
                              void* d_out, int out_size, void* d_ws, size_t ws_size,
                              hipStream_t stream) {
    const float* x = (const float*)d_in[0];        // (4,3,128,128) f32
    const float* w = (const float*)d_in[1];        // (3,2,4,3) f32
    float* out = (float*)d_out;                    // (4,8,128,128) f32
    const int total = 4 * 128 * 128 * 2;           // 2 threads per pixel
    qconv_kernel<<<total / 512, 512, 0, stream>>>(x, w, out);
}